// Round 1
// 80.698 us; speedup vs baseline: 1.0819x; 1.0819x over previous
//
#include <hip/hip_runtime.h>

#define NNODES 1024
#define NHEADS 8
#define NHID 16
#define DIM 128            // NHEADS * NHID
#define NEG_SLOPE 0.2f

// quad broadcast via DPP quad_perm (replaces ds_bpermute __shfl within 4-lane group)
template<int CTRL>
__device__ __forceinline__ float qbcast(float v) {
    return __int_as_float(__builtin_amdgcn_mov_dpp(__float_as_int(v), CTRL, 0xF, 0xF, true));
}

// K1: g = h @ W^T tiled 16(i) x 16(one head); src/dst reductions fused.
// h-tile and W-tile staged in padded LDS -> ds_read_b128, conflict-free,
// coalesced global stages (old version: lane l read W row l => 64-line loads).
__global__ __launch_bounds__(256) void proj_kernel(
    const float* __restrict__ h, const float* __restrict__ W,
    const float* __restrict__ attn_w,
    float* __restrict__ g, float* __restrict__ srcv, float* __restrict__ dstv)
{
    const int bi = blockIdx.x & 63;   // i-tile
    const int bh = blockIdx.x >> 6;   // head
    const int i0 = bi << 4;
    const int tid = threadIdx.x;
    __shared__ float4 hs[16][33];     // +1 float4 pad: banks spread
    __shared__ float4 ws[16][33];
    const float4* h4 = (const float4*)h;   // 32 float4 per row
    const float4* W4 = (const float4*)W;
    {
        const int t0 = tid, t1 = tid + 256;
        hs[t0 >> 5][t0 & 31] = h4[(size_t)i0 * 32 + t0];
        hs[t1 >> 5][t1 & 31] = h4[(size_t)i0 * 32 + t1];
        ws[t0 >> 5][t0 & 31] = W4[(size_t)(bh * 16) * 32 + t0];
        ws[t1 >> 5][t1 & 31] = W4[(size_t)(bh * 16) * 32 + t1];
    }
    __syncthreads();
    const int il = tid >> 4;          // 0..15 local row
    const int f  = tid & 15;          // 0..15 feature within head
    float acc = 0.f;
#pragma unroll
    for (int k = 0; k < 32; k++) {
        const float4 a = hs[il][k];
        const float4 b = ws[f][k];
        acc = fmaf(a.x, b.x, fmaf(a.y, b.y, fmaf(a.z, b.z, fmaf(a.w, b.w, acc))));
    }
    const int i = i0 + il;
    g[(size_t)i * DIM + bh * NHID + f] = acc;
    float sv = acc * attn_w[f];
    float dv = acc * attn_w[NHID + f];
#pragma unroll
    for (int off = 1; off <= 8; off <<= 1) {
        sv += __shfl_xor(sv, off, 64);   // reduce over f (lane bits 0..3)
        dv += __shfl_xor(dv, off, 64);
    }
    if (f == 0) { srcv[i * NHEADS + bh] = sv; dstv[i * NHEADS + bh] = dv; }
}

// K2: 2 rows per block, 512 threads (8 waves) -> 2 blocks/CU = 4 waves/SIMD
// (was 256 threads -> 2 waves/SIMD, latency-bound). Quad w-broadcast via DPP.
__global__ __launch_bounds__(512, 4) void fused_kernel(
    const int* __restrict__ adj, const float* __restrict__ s,
    const float* __restrict__ g, const float* __restrict__ srcv,
    const float* __restrict__ dstv, float* __restrict__ out)
{
    const int i0   = blockIdx.x * 2;
    const int tid  = threadIdx.x;
    const int lane = tid & 63;
    const int wv   = tid >> 6;            // wave 0..7

    __shared__ float evL[2][NNODES];          // 8 KB: adj ? exp(s) : 0
    __shared__ float dstL[NNODES * NHEADS];   // 32 KB staged dstv
    __shared__ float sh_src[2][NHEADS];
    __shared__ float zeA[8][NHEADS][2];
    __shared__ float zsA[8];
    __shared__ float statE[2][NHEADS];
    __shared__ float statS[2];
    __shared__ float redO[8][2][NHEADS][4][4];  // 8 KB
    __shared__ float ztA[8][2][NHEADS];

    // ---- Phase A1: ev into LDS; zs partial; stage dstv + srcv ----
    const int rA = tid >> 8;              // waves 0-3 -> row 0, waves 4-7 -> row 1
    const int cA = tid & 255;
    float zs;
    {
        const int4   a  = ((const int4*)  adj)[(size_t)(i0 + rA) * (NNODES/4) + cA];
        const float4 sv = ((const float4*)s  )[(size_t)(i0 + rA) * (NNODES/4) + cA];
        float4 e4;
        e4.x = a.x ? __expf(sv.x) : 0.f;
        e4.y = a.y ? __expf(sv.y) : 0.f;
        e4.z = a.z ? __expf(sv.z) : 0.f;
        e4.w = a.w ? __expf(sv.w) : 0.f;
        ((float4*)evL[rA])[cA] = e4;
        zs = e4.x + e4.y + e4.z + e4.w;
    }
    {
        const float4* dv4 = (const float4*)dstv;
        float4* dl4 = (float4*)dstL;
#pragma unroll
        for (int k = 0; k < 4; k++) dl4[k * 512 + tid] = dv4[k * 512 + tid];
        if (tid < 16) sh_src[tid >> 3][tid & 7] =
            srcv[(size_t)(i0 + (tid >> 3)) * NHEADS + (tid & 7)];
    }
#pragma unroll
    for (int off = 1; off <= 32; off <<= 1) zs += __shfl_xor(zs, off, 64);
    if (lane == 0) zsA[wv] = zs;          // wave's row is rA (uniform per wave)
    __syncthreads();

    // ---- Phase A2: ze[r][h] over unmasked j ----
    const int hA  = tid & 7;
    const int jsA = tid >> 3;             // 0..63
    float ze0 = 0.f, ze1 = 0.f;
    {
        const float sH0 = sh_src[0][hA], sH1 = sh_src[1][hA];
#pragma unroll 4
        for (int t = 0; t < 16; t++) {
            const int j = t * 64 + jsA;
            const float d = dstL[j * NHEADS + hA];
            float e0 = sH0 + d; e0 = e0 > 0.f ? e0 : NEG_SLOPE * e0;
            float e1 = sH1 + d; e1 = e1 > 0.f ? e1 : NEG_SLOPE * e1;
            ze0 += (evL[0][j] != 0.f) ? __expf(e0) : 0.f;
            ze1 += (evL[1][j] != 0.f) ? __expf(e1) : 0.f;
        }
    }
#pragma unroll
    for (int off = 8; off <= 32; off <<= 1) {
        ze0 += __shfl_xor(ze0, off, 64);
        ze1 += __shfl_xor(ze1, off, 64);
    }
    if (lane < NHEADS) { zeA[wv][lane][0] = ze0; zeA[wv][lane][1] = ze1; }
    __syncthreads();
    if (tid < 16) {
        const int hh = tid & 7, rr = tid >> 3;
        float z = 0.f;
#pragma unroll
        for (int w2 = 0; w2 < 8; w2++) z += zeA[w2][hh][rr];
        statE[rr][hh] = 1.f / z;
    } else if (tid < 18) {
        const int rr = tid - 16;
        statS[rr] = 1.f / (zsA[rr*4] + zsA[rr*4+1] + zsA[rr*4+2] + zsA[rr*4+3]);
    }
    __syncthreads();

    // ---- Phase B: tid = jsB*32 + hB*4 + qB ----
    const int qB  = tid & 3;
    const int hB  = (tid >> 2) & 7;
    const int jsB = tid >> 5;             // 0..15
    const float ize0 = statE[0][hB], ize1 = statE[1][hB];
    const float izs0 = statS[0],     izs1 = statS[1];
    const float sB0  = sh_src[0][hB], sB1 = sh_src[1][hB];

    float acc0[4] = {0.f,0.f,0.f,0.f};
    float acc1[4] = {0.f,0.f,0.f,0.f};
    float zt0 = 0.f, zt1 = 0.f;
    const float4* g4 = (const float4*)g;
    const int jw0   = qB * 16 + jsB;              // this lane's w-j (mod 64)
    const int gidx0 = jsB * 32 + hB * 4 + qB;     // float4 index base

#pragma unroll 2
    for (int tg = 0; tg < 16; tg++) {
        const int jw = tg * 64 + jw0;
        const float d = dstL[jw * NHEADS + hB];
        float e0 = sB0 + d; e0 = e0 > 0.f ? e0 : NEG_SLOPE * e0;
        float e1 = sB1 + d; e1 = e1 > 0.f ? e1 : NEG_SLOPE * e1;
        const float x0 = __expf(e0), x1 = __expf(e1);
        const float ev0 = evL[0][jw], ev1 = evL[1][jw];
        const float a0 = (ev0 != 0.f) ? fmaf(x0, ize0, ev0 * izs0) : 0.f;
        const float a1 = (ev1 != 0.f) ? fmaf(x1, ize1, ev1 * izs1) : 0.f;
        const float w0 = __expf(a0), w1 = __expf(a1);   // exp(0)=1 at masked
        zt0 += w0; zt1 += w1;

#define KSTEP(K, CTRL)                                                        \
        {                                                                     \
            const float w0k = qbcast<CTRL>(w0);                               \
            const float w1k = qbcast<CTRL>(w1);                               \
            const float4 gv = g4[gidx0 + tg * 2048 + (K) * 512];              \
            acc0[0] = fmaf(w0k, gv.x, acc0[0]);                               \
            acc0[1] = fmaf(w0k, gv.y, acc0[1]);                               \
            acc0[2] = fmaf(w0k, gv.z, acc0[2]);                               \
            acc0[3] = fmaf(w0k, gv.w, acc0[3]);                               \
            acc1[0] = fmaf(w1k, gv.x, acc1[0]);                               \
            acc1[1] = fmaf(w1k, gv.y, acc1[1]);                               \
            acc1[2] = fmaf(w1k, gv.z, acc1[2]);                               \
            acc1[3] = fmaf(w1k, gv.w, acc1[3]);                               \
        }
        KSTEP(0, 0x00)
        KSTEP(1, 0x55)
        KSTEP(2, 0xAA)
        KSTEP(3, 0xFF)
#undef KSTEP
    }

    // ---- Epilogue ----
#pragma unroll
    for (int m = 0; m < 4; m++) {
        acc0[m] += __shfl_xor(acc0[m], 32, 64);   // reduce jsB bit inside wave
        acc1[m] += __shfl_xor(acc1[m], 32, 64);
    }
    zt0 += __shfl_xor(zt0, 1, 64); zt0 += __shfl_xor(zt0, 2, 64); zt0 += __shfl_xor(zt0, 32, 64);
    zt1 += __shfl_xor(zt1, 1, 64); zt1 += __shfl_xor(zt1, 2, 64); zt1 += __shfl_xor(zt1, 32, 64);
    if (lane < 32) {
        *(float4*)&redO[wv][0][hB][qB][0] = make_float4(acc0[0], acc0[1], acc0[2], acc0[3]);
        *(float4*)&redO[wv][1][hB][qB][0] = make_float4(acc1[0], acc1[1], acc1[2], acc1[3]);
        if ((lane & 3) == 0) { ztA[wv][0][hB] = zt0; ztA[wv][1][hB] = zt1; }
    }
    __syncthreads();
    if (tid < 256) {
        const int rr = tid >> 7;
        const int hf = tid & 127;
        const int oh = hf >> 4;
        const int qq = (hf >> 2) & 3;
        const int mm = hf & 3;
        float v = 0.f, z = 0.f;
#pragma unroll
        for (int w2 = 0; w2 < 8; w2++) {
            v += redO[w2][rr][oh][qq][mm];
            z += ztA[w2][rr][oh];
        }
        out[(size_t)(i0 + rr) * DIM + hf] = v / z;
    }
}

extern "C" void kernel_launch(void* const* d_in, const int* in_sizes, int n_in,
                              void* d_out, int out_size, void* d_ws, size_t ws_size,
                              hipStream_t stream) {
    const float* h      = (const float*)d_in[0];
    const int*   adj    = (const int*)  d_in[1];
    const float* s      = (const float*)d_in[2];
    const float* W      = (const float*)d_in[3];
    const float* attn_w = (const float*)d_in[4];
    float* out = (float*)d_out;

    float* g    = (float*)d_ws;                      // 1024*128
    float* srcv = g    + (size_t)NNODES * DIM;       // 1024*8
    float* dstv = srcv + (size_t)NNODES * NHEADS;    // 1024*8

    proj_kernel <<<512, 256, 0, stream>>>(h, W, attn_w, g, srcv, dstv);
    fused_kernel<<<NNODES / 2, 512, 0, stream>>>(adj, s, g, srcv, dstv, out);
}